// Round 11
// baseline (566.836 us; speedup 1.0000x reference)
//
#include <hip/hip_runtime.h>

#define EPS_LN 1e-4f

typedef short short8 __attribute__((ext_vector_type(8)));
typedef float f32x4 __attribute__((ext_vector_type(4)));

// f32 -> bf16 round-to-nearest-even (bit trick, 3 VALU)
__device__ __forceinline__ short f2bf(float f) {
  const unsigned u = __float_as_uint(f);
  return (short)((u + 0x7FFFu + ((u >> 16) & 1u)) >> 16);
}

// ===========================================================================
// r10 evidence: total 541us; budget math puts conv_mfma at ~300-320us
// (740MB @ 2.3TB/s) -- gather latency exposed per 64-rule group (only the
// INDICES were prefetched, not the feats rows). normalize ~165 (roofline),
// flag ~15-30, zero ~20.
// r11: conv gets a 2-deep A/B group pipeline (T14 issue-early/consume-late):
// group B's 8 gather-dwordx4 are in flight while group A's tiles compute.
// A/B unrolled x2, no register copies, static indexing. Everything else
// unchanged from r10.
// ws: [0,1KB) stats | [2KB) flags[(n_out+16)/16 + 1 words]
// ===========================================================================

__global__ __launch_bounds__(256) void flag_kernel(
    const int* __restrict__ sidx, unsigned* __restrict__ flags, int P,
    int n_out) {
  const int k = blockIdx.y;
  const int p = blockIdx.x * blockDim.x + threadIdx.x;
  if (p >= P) return;
  const int s = sidx[k * P + p];
  if (s >= n_out) return;  // padding
  const unsigned sh = (s & 15) << 1;
  const unsigned old = atomicOr(&flags[s >> 4], 1u << sh);
  if (old & (1u << sh)) atomicOr(&flags[s >> 4], 2u << sh);  // multi (rare)
}

__global__ __launch_bounds__(256) void zero_multi_kernel(
    const unsigned* __restrict__ flags, float4* __restrict__ out, int nwords,
    int n_out) {
  const int stride = gridDim.x * blockDim.x;
  const float4 z = {0.f, 0.f, 0.f, 0.f};
  for (int w = blockIdx.x * blockDim.x + threadIdx.x; w < nwords; w += stride) {
    unsigned f = flags[w] & 0xAAAAAAAAu;  // multi bits
    while (f) {
      const int b = __builtin_ctz(f);
      f &= f - 1;
      const int r = (w << 4) + (b >> 1);
      if (r < n_out) {
        float4* row = out + ((size_t)r << 4);  // 64 floats
#pragma unroll
        for (int j = 0; j < 16; ++j) row[j] = z;
      }
    }
  }
}

// ---- conv helpers (all force-inlined, static indexing only) ----

__device__ __forceinline__ void load_idx(
    const int* __restrict__ gidx, const int* __restrict__ sidx,
    const unsigned* __restrict__ flags, long base, int pg, int end_,
    int n_out, int& g, int& sp) {
  g = 0;
  sp = (n_out << 1);
  if (pg < end_) {
    g = gidx[base + pg];
    const int s = sidx[base + pg];
    const unsigned mu = (flags[s >> 4] >> (((s & 15) << 1) + 1)) & 1u;
    sp = (s << 1) | (int)mu;
  }
}

__device__ __forceinline__ void gather8(const float* __restrict__ feats,
                                        int g, int l15, int lh, float4* F) {
#pragma unroll
  for (int t = 0; t < 4; ++t) {
    const int gq = __shfl(g, (t << 4) + l15);  // rule owning my A-row
    const float4* fp = (const float4*)feats + ((size_t)gq << 3) + (lh << 1);
    F[2 * t] = fp[0];
    F[2 * t + 1] = fp[1];
  }
}

__device__ __forceinline__ void compute_store(
    const float4* F, int sp, const short8* wb, int l15, int lh,
    float* __restrict__ out, int n_out, float* s1, float* s2) {
  const f32x4 zero = {0.f, 0.f, 0.f, 0.f};
#pragma unroll
  for (int t = 0; t < 4; ++t) {
    short8 a;
#pragma unroll
    for (int j = 0; j < 4; ++j) {
      a[j] = f2bf(((const float*)&F[2 * t])[j]);
      a[4 + j] = f2bf(((const float*)&F[2 * t + 1])[j]);
    }
    const f32x4 d0 = __builtin_amdgcn_mfma_f32_16x16x32_bf16(a, wb[0], zero, 0, 0, 0);
    const f32x4 d1 = __builtin_amdgcn_mfma_f32_16x16x32_bf16(a, wb[1], zero, 0, 0, 0);
    const f32x4 d2 = __builtin_amdgcn_mfma_f32_16x16x32_bf16(a, wb[2], zero, 0, 0, 0);
    const f32x4 d3 = __builtin_amdgcn_mfma_f32_16x16x32_bf16(a, wb[3], zero, 0, 0, 0);
#pragma unroll
    for (int q = 0; q < 4; ++q) {
      const int spq = __shfl(sp, (t << 4) + (lh << 2) + q);  // rule 4lh+q
      const int srow = spq >> 1;
      const bool mu = (spq & 1) != 0;
      const bool v = srow < n_out;
      const size_t rb = ((size_t)srow << 6) + l15;
#define DO_STORE(dm, m)                                             \
      {                                                             \
        const float val = dm[q];                                    \
        if (v) {                                                    \
          s1[m] += val;                                             \
          if (mu) {                                                 \
            const float old = atomicAdd(out + rb + (m << 4), val);  \
            s2[m] = fmaf(val, 2.f * old + val, s2[m]);              \
          } else {                                                  \
            out[rb + (m << 4)] = val;                               \
            s2[m] = fmaf(val, val, s2[m]);                          \
          }                                                         \
        }                                                           \
      }
      DO_STORE(d0, 0)
      DO_STORE(d1, 1)
      DO_STORE(d2, 2)
      DO_STORE(d3, 3)
#undef DO_STORE
    }
  }
}

__global__ __launch_bounds__(256) void conv_mfma_kernel(
    const float* __restrict__ feats, const float* __restrict__ W,
    const int* __restrict__ gidx, const int* __restrict__ sidx,
    const unsigned* __restrict__ flags, float* __restrict__ out,
    float* __restrict__ ws, int P, int n_out, int rpw) {
  const int lane = threadIdx.x & 63;
  const int l15 = lane & 15;
  const int lh = lane >> 4;  // 0..3
  const int k = blockIdx.y;
  const int wv = blockIdx.x * (blockDim.x >> 6) + (threadIdx.x >> 6);

  __shared__ float ls[128];
  if (threadIdx.x < 128) ls[threadIdx.x] = 0.f;
  __syncthreads();

  // B fragments: wb[m][j] = W[k][ 8*lh+j ][ 16m + l15 ] as bf16
  short8 wb[4];
#pragma unroll
  for (int m = 0; m < 4; ++m) {
#pragma unroll
    for (int j = 0; j < 8; ++j) {
      const int kk = (lh << 3) + j;
      wb[m][j] = f2bf(W[(((k << 5) + kk) << 6) + (m << 4) + l15]);
    }
  }

  const long base = (long)k * P;
  const int start = wv * rpw;
  const int end = min(start + rpw, P);
  float s1[4] = {0.f, 0.f, 0.f, 0.f}, s2[4] = {0.f, 0.f, 0.f, 0.f};

  if (start < end) {
    int gA, spA, gB, spB, gC, spC, gD, spD;
    float4 FA[8], FB[8];

    // prologue: idx(A0) -> gather(A0) -> idx(B0)
    load_idx(gidx, sidx, flags, base, start + lane, end, n_out, gA, spA);
    gather8(feats, gA, l15, lh, FA);
    load_idx(gidx, sidx, flags, base, start + 64 + lane, end, n_out, gB, spB);

    for (int gs = start; gs < end; gs += 128) {
      const bool hasB = (gs + 64 < end);
      // issue B's gathers before consuming A (B in flight under A's compute)
      if (hasB) gather8(feats, gB, l15, lh, FB);
      load_idx(gidx, sidx, flags, base, gs + 128 + lane, end, n_out, gC, spC);
      compute_store(FA, spA, wb, l15, lh, out, n_out, s1, s2);
      // issue next A's gathers before consuming B
      if (gs + 128 < end) gather8(feats, gC, l15, lh, FA);
      load_idx(gidx, sidx, flags, base, gs + 192 + lane, end, n_out, gD, spD);
      if (hasB) compute_store(FB, spB, wb, l15, lh, out, n_out, s1, s2);
      gA = gC; spA = spC;
      gB = gD; spB = spD;
    }
  }

#pragma unroll
  for (int m = 0; m < 4; ++m) {
    atomicAdd(&ls[(m << 4) + l15], s1[m]);
    atomicAdd(&ls[64 + (m << 4) + l15], s2[m]);
  }
  __syncthreads();
  if (threadIdx.x < 128) atomicAdd(&ws[threadIdx.x], ls[threadIdx.x]);
}

__global__ void finalize_stats_kernel(float* __restrict__ ws,
                                      const float* __restrict__ gamma,
                                      const float* __restrict__ beta,
                                      float inv_n) {
  const int c = threadIdx.x;  // 64 threads
  const float mean = ws[c] * inv_n;
  const float var = ws[64 + c] * inv_n - mean * mean;
  const float sc = rsqrtf(var + EPS_LN) * gamma[c];
  ws[128 + c] = sc;
  ws[192 + c] = beta[c] - mean * sc;
}

__global__ __launch_bounds__(256) void normalize_kernel(
    float4* __restrict__ out, const float* __restrict__ ws, long total4) {
  const long stride = (long)gridDim.x * blockDim.x;
  const int cb = (threadIdx.x << 2) & 63;
  const float4 sc = *(const float4*)(ws + 128 + cb);
  const float4 sh = *(const float4*)(ws + 192 + cb);
  for (long i = (long)blockIdx.x * blockDim.x + threadIdx.x; i < total4; i += stride) {
    float4 x = out[i];
    x.x = fmaxf(fmaf(x.x, sc.x, sh.x), 0.f);
    x.y = fmaxf(fmaf(x.y, sc.y, sh.y), 0.f);
    x.z = fmaxf(fmaf(x.z, sc.z, sh.z), 0.f);
    x.w = fmaxf(fmaf(x.w, sc.w, sh.w), 0.f);
    out[i] = x;
  }
}

// ---------------- fallback (if ws too small): r2 path ----------------
__global__ __launch_bounds__(256) void scatter_conv_kernel(
    const float* __restrict__ feats, const float* __restrict__ W,
    const int* __restrict__ gidx, const int* __restrict__ sidx,
    float* __restrict__ out, int P, int n_out) {
  const int lane = threadIdx.x & 63;
  const int k = blockIdx.y;
  const int wave = blockIdx.x * (blockDim.x >> 6) + (threadIdx.x >> 6);
  const int stride = gridDim.x * (blockDim.x >> 6);
  float w[32];
#pragma unroll
  for (int c = 0; c < 32; ++c) w[c] = W[((k * 32 + c) << 6) + lane];
  const int base = k * P;
  for (int p = wave; p < P; p += stride) {
    const int g = gidx[base + p];
    const int s = sidx[base + p];
    const float4* fp = (const float4*)(feats + (long)g * 32);
    float4 f[8];
#pragma unroll
    for (int j = 0; j < 8; ++j) f[j] = fp[j];
    float a0 = 0, a1 = 0, a2 = 0, a3 = 0;
#pragma unroll
    for (int j = 0; j < 8; ++j) {
      a0 = fmaf(f[j].x, w[4 * j + 0], a0);
      a1 = fmaf(f[j].y, w[4 * j + 1], a1);
      a2 = fmaf(f[j].z, w[4 * j + 2], a2);
      a3 = fmaf(f[j].w, w[4 * j + 3], a3);
    }
    if (s < n_out) atomicAdd(out + ((long)s << 6) + lane, (a0 + a1) + (a2 + a3));
  }
}

__global__ __launch_bounds__(256) void stats_kernel(
    const float4* __restrict__ out, float* __restrict__ ws, long total4) {
  const long stride = (long)gridDim.x * blockDim.x;
  float s1[4] = {0.f, 0.f, 0.f, 0.f};
  float s2[4] = {0.f, 0.f, 0.f, 0.f};
  for (long i = (long)blockIdx.x * blockDim.x + threadIdx.x; i < total4; i += stride) {
    float4 x = out[i];
    s1[0] += x.x; s2[0] += x.x * x.x;
    s1[1] += x.y; s2[1] += x.y * x.y;
    s1[2] += x.z; s2[2] += x.z * x.z;
    s1[3] += x.w; s2[3] += x.w * x.w;
  }
  __shared__ float ls[128];
  if (threadIdx.x < 128) ls[threadIdx.x] = 0.f;
  __syncthreads();
  const int cb = (threadIdx.x << 2) & 63;
#pragma unroll
  for (int j = 0; j < 4; ++j) {
    atomicAdd(&ls[cb + j], s1[j]);
    atomicAdd(&ls[64 + cb + j], s2[j]);
  }
  __syncthreads();
  if (threadIdx.x < 128) atomicAdd(&ws[threadIdx.x], ls[threadIdx.x]);
}

extern "C" void kernel_launch(void* const* d_in, const int* in_sizes, int n_in,
                              void* d_out, int out_size, void* d_ws, size_t ws_size,
                              hipStream_t stream) {
  const float* feats = (const float*)d_in[0];
  const float* W     = (const float*)d_in[1];
  const float* gamma = (const float*)d_in[2];
  const float* beta  = (const float*)d_in[3];
  const int*   gidx  = (const int*)d_in[4];
  const int*   sidx  = (const int*)d_in[5];

  const int P = in_sizes[4] / 4;    // KVOL == 4
  const int n_out = out_size / 64;  // COUT == 64
  float* out = (float*)d_out;
  float* ws  = (float*)d_ws;
  const long total4 = (long)out_size / 4;

  char* wsb = (char*)d_ws;
  const size_t flags_off = 2048;
  const int nwords = (n_out + 16) / 16 + 1;  // covers s == n_out padding word
  const size_t flags_bytes = (size_t)nwords * 4;
  const size_t need = flags_off + flags_bytes;

  if (ws_size >= need) {
    unsigned* flags = (unsigned*)(wsb + flags_off);
    hipMemsetAsync(wsb, 0, 2048, stream);           // stats block
    hipMemsetAsync(flags, 0, flags_bytes, stream);  // flag table (486 KB)

    dim3 fgrid((P + 255) / 256, 4);
    flag_kernel<<<fgrid, 256, 0, stream>>>(sidx, flags, P, n_out);
    zero_multi_kernel<<<1024, 256, 0, stream>>>(flags, (float4*)out, nwords, n_out);

    const int rpw = 256;  // rules per wave (4 groups of 64 = 2 A/B pairs)
    const int waves_per_k = (P + rpw - 1) / rpw;
    dim3 vgrid((waves_per_k + 3) / 4, 4);
    conv_mfma_kernel<<<vgrid, 256, 0, stream>>>(feats, W, gidx, sidx, flags,
                                                out, ws, P, n_out, rpw);
    finalize_stats_kernel<<<1, 64, 0, stream>>>(ws, gamma, beta, 1.0f / (float)n_out);
    normalize_kernel<<<2048, 256, 0, stream>>>((float4*)out, ws, total4);
  } else {
    hipMemsetAsync(d_out, 0, (size_t)out_size * sizeof(float), stream);
    hipMemsetAsync(d_ws, 0, 256 * sizeof(float), stream);
    dim3 sgrid(2048, 4);
    scatter_conv_kernel<<<sgrid, 256, 0, stream>>>(feats, W, gidx, sidx, out, P, n_out);
    stats_kernel<<<2048, 256, 0, stream>>>((const float4*)out, ws, total4);
    finalize_stats_kernel<<<1, 64, 0, stream>>>(ws, gamma, beta, 1.0f / (float)n_out);
    normalize_kernel<<<2048, 256, 0, stream>>>((float4*)out, ws, total4);
  }
}

// Round 12
// 534.572 us; speedup vs baseline: 1.0604x; 1.0604x over previous
//
#include <hip/hip_runtime.h>

#define EPS_LN 1e-4f

typedef short short8 __attribute__((ext_vector_type(8)));
typedef float f32x4 __attribute__((ext_vector_type(4)));
typedef int int4v __attribute__((ext_vector_type(4)));

// f32 -> bf16 RTNE (bit trick; used only in one-time W setup)
__device__ __forceinline__ short f2bf(float f) {
  const unsigned u = __float_as_uint(f);
  return (short)((u + 0x7FFFu + ((u >> 16) & 1u)) >> 16);
}

// pack 2 f32 -> 2 bf16 in one VALU op (RTNE, same rounding as f2bf)
__device__ __forceinline__ int cvt_pk_bf16(float lo, float hi) {
  int r;
  asm("v_cvt_pk_bf16_f32 %0, %1, %2" : "=v"(r) : "v"(lo), "v"(hi));
  return r;
}

// ===========================================================================
// r11 post-mortem: explicit 2-deep gather pipeline REGRESSED (541->567us);
// wave-level TLP already covers gather latency (8x1KB in flight per wave).
// r12 = exact r10 structure (541us baseline) + one VALU cut in conv:
// A-fragment f32->bf16 via v_cvt_pk_bf16_f32 (4 instr/tile vs ~32).
// Discriminator: if total stays ~541, conv sits at the random-access memory
// wall (268MB random 128B reads + 500MB scattered 64B writes) -> roofline.
// ws: [0,1KB) stats | [2KB) flags[(n_out+16)/16 + 1 words]
// ===========================================================================

__global__ __launch_bounds__(256) void flag_kernel(
    const int* __restrict__ sidx, unsigned* __restrict__ flags, int P,
    int n_out) {
  const int k = blockIdx.y;
  const int p = blockIdx.x * blockDim.x + threadIdx.x;
  if (p >= P) return;
  const int s = sidx[k * P + p];
  if (s >= n_out) return;  // padding
  const unsigned sh = (s & 15) << 1;
  const unsigned old = atomicOr(&flags[s >> 4], 1u << sh);
  if (old & (1u << sh)) atomicOr(&flags[s >> 4], 2u << sh);  // multi (rare)
}

__global__ __launch_bounds__(256) void zero_multi_kernel(
    const unsigned* __restrict__ flags, float4* __restrict__ out, int nwords,
    int n_out) {
  const int stride = gridDim.x * blockDim.x;
  const float4 z = {0.f, 0.f, 0.f, 0.f};
  for (int w = blockIdx.x * blockDim.x + threadIdx.x; w < nwords; w += stride) {
    unsigned f = flags[w] & 0xAAAAAAAAu;  // multi bits
    while (f) {
      const int b = __builtin_ctz(f);
      f &= f - 1;
      const int r = (w << 4) + (b >> 1);
      if (r < n_out) {
        float4* row = out + ((size_t)r << 4);  // 64 floats
#pragma unroll
        for (int j = 0; j < 16; ++j) row[j] = z;
      }
    }
  }
}

__global__ __launch_bounds__(256) void conv_mfma_kernel(
    const float* __restrict__ feats, const float* __restrict__ W,
    const int* __restrict__ gidx, const int* __restrict__ sidx,
    const unsigned* __restrict__ flags, float* __restrict__ out,
    float* __restrict__ ws, int P, int n_out, int rpw) {
  const int lane = threadIdx.x & 63;
  const int l15 = lane & 15;
  const int lh = lane >> 4;  // 0..3
  const int k = blockIdx.y;
  const int wv = blockIdx.x * (blockDim.x >> 6) + (threadIdx.x >> 6);

  __shared__ float ls[128];
  if (threadIdx.x < 128) ls[threadIdx.x] = 0.f;
  __syncthreads();

  // B fragments: wb[m][j] = W[k][ 8*lh+j ][ 16m + l15 ] as bf16
  short8 wb[4];
#pragma unroll
  for (int m = 0; m < 4; ++m) {
#pragma unroll
    for (int j = 0; j < 8; ++j) {
      const int kk = (lh << 3) + j;
      wb[m][j] = f2bf(W[(((k << 5) + kk) << 6) + (m << 4) + l15]);
    }
  }

  const long base = (long)k * P;
  const int start = wv * rpw;
  const int end = min(start + rpw, P);
  float s1[4] = {0.f, 0.f, 0.f, 0.f}, s2[4] = {0.f, 0.f, 0.f, 0.f};
  const f32x4 zero = {0.f, 0.f, 0.f, 0.f};

  if (start < end) {
    // group (64 rules) index state; sp = (s<<1) | multi
    int g = 0, sp = (n_out << 1);
    {
      const int pg = start + lane;
      if (pg < end) {
        g = gidx[base + pg];
        const int s = sidx[base + pg];
        const unsigned mu = (flags[s >> 4] >> (((s & 15) << 1) + 1)) & 1u;
        sp = (s << 1) | (int)mu;
      }
    }

    for (int gs = start; gs < end; gs += 64) {
      // ---- issue all 4 tiles' gathers: 64 random 128B rows in flight ----
      float4 F[8];
#pragma unroll
      for (int t = 0; t < 4; ++t) {
        const int gq = __shfl(g, (t << 4) + l15);  // rule for my A-row
        const float4* fp = (const float4*)feats + ((size_t)gq << 3) + (lh << 1);
        F[2 * t] = fp[0];
        F[2 * t + 1] = fp[1];
      }
      // ---- prefetch next group's indices under this group's compute ----
      int gN = 0, spN = (n_out << 1);
      {
        const int pg = gs + 64 + lane;
        if (pg < end) {
          gN = gidx[base + pg];
          const int s = sidx[base + pg];
          const unsigned mu = (flags[s >> 4] >> (((s & 15) << 1) + 1)) & 1u;
          spN = (s << 1) | (int)mu;
        }
      }
      // ---- per tile: cvt_pk -> 4 MFMA -> classified store + stats ----
#pragma unroll
      for (int t = 0; t < 4; ++t) {
        int4v au;
        au.x = cvt_pk_bf16(F[2 * t].x, F[2 * t].y);
        au.y = cvt_pk_bf16(F[2 * t].z, F[2 * t].w);
        au.z = cvt_pk_bf16(F[2 * t + 1].x, F[2 * t + 1].y);
        au.w = cvt_pk_bf16(F[2 * t + 1].z, F[2 * t + 1].w);
        const short8 a = __builtin_bit_cast(short8, au);
        const f32x4 d0 = __builtin_amdgcn_mfma_f32_16x16x32_bf16(a, wb[0], zero, 0, 0, 0);
        const f32x4 d1 = __builtin_amdgcn_mfma_f32_16x16x32_bf16(a, wb[1], zero, 0, 0, 0);
        const f32x4 d2 = __builtin_amdgcn_mfma_f32_16x16x32_bf16(a, wb[2], zero, 0, 0, 0);
        const f32x4 d3 = __builtin_amdgcn_mfma_f32_16x16x32_bf16(a, wb[3], zero, 0, 0, 0);
#pragma unroll
        for (int q = 0; q < 4; ++q) {
          const int spq = __shfl(sp, (t << 4) + (lh << 2) + q);  // rule 4lh+q
          const int srow = spq >> 1;
          const bool mu = (spq & 1) != 0;
          const bool v = srow < n_out;
          const size_t rb = ((size_t)srow << 6) + l15;
#define DO_STORE(dm, m)                                                 \
          {                                                             \
            const float val = dm[q];                                    \
            if (v) {                                                    \
              s1[m] += val;                                             \
              if (mu) {                                                 \
                const float old = atomicAdd(out + rb + (m << 4), val);  \
                s2[m] = fmaf(val, 2.f * old + val, s2[m]);              \
              } else {                                                  \
                out[rb + (m << 4)] = val;                               \
                s2[m] = fmaf(val, val, s2[m]);                          \
              }                                                         \
            }                                                           \
          }
          DO_STORE(d0, 0)
          DO_STORE(d1, 1)
          DO_STORE(d2, 2)
          DO_STORE(d3, 3)
#undef DO_STORE
        }
      }
      g = gN;
      sp = spN;
    }
  }

#pragma unroll
  for (int m = 0; m < 4; ++m) {
    atomicAdd(&ls[(m << 4) + l15], s1[m]);
    atomicAdd(&ls[64 + (m << 4) + l15], s2[m]);
  }
  __syncthreads();
  if (threadIdx.x < 128) atomicAdd(&ws[threadIdx.x], ls[threadIdx.x]);
}

__global__ void finalize_stats_kernel(float* __restrict__ ws,
                                      const float* __restrict__ gamma,
                                      const float* __restrict__ beta,
                                      float inv_n) {
  const int c = threadIdx.x;  // 64 threads
  const float mean = ws[c] * inv_n;
  const float var = ws[64 + c] * inv_n - mean * mean;
  const float sc = rsqrtf(var + EPS_LN) * gamma[c];
  ws[128 + c] = sc;
  ws[192 + c] = beta[c] - mean * sc;
}

__global__ __launch_bounds__(256) void normalize_kernel(
    float4* __restrict__ out, const float* __restrict__ ws, long total4) {
  const long stride = (long)gridDim.x * blockDim.x;
  const int cb = (threadIdx.x << 2) & 63;
  const float4 sc = *(const float4*)(ws + 128 + cb);
  const float4 sh = *(const float4*)(ws + 192 + cb);
  for (long i = (long)blockIdx.x * blockDim.x + threadIdx.x; i < total4; i += stride) {
    float4 x = out[i];
    x.x = fmaxf(fmaf(x.x, sc.x, sh.x), 0.f);
    x.y = fmaxf(fmaf(x.y, sc.y, sh.y), 0.f);
    x.z = fmaxf(fmaf(x.z, sc.z, sh.z), 0.f);
    x.w = fmaxf(fmaf(x.w, sc.w, sh.w), 0.f);
    out[i] = x;
  }
}

// ---------------- fallback (if ws too small): r2 path ----------------
__global__ __launch_bounds__(256) void scatter_conv_kernel(
    const float* __restrict__ feats, const float* __restrict__ W,
    const int* __restrict__ gidx, const int* __restrict__ sidx,
    float* __restrict__ out, int P, int n_out) {
  const int lane = threadIdx.x & 63;
  const int k = blockIdx.y;
  const int wave = blockIdx.x * (blockDim.x >> 6) + (threadIdx.x >> 6);
  const int stride = gridDim.x * (blockDim.x >> 6);
  float w[32];
#pragma unroll
  for (int c = 0; c < 32; ++c) w[c] = W[((k * 32 + c) << 6) + lane];
  const int base = k * P;
  for (int p = wave; p < P; p += stride) {
    const int g = gidx[base + p];
    const int s = sidx[base + p];
    const float4* fp = (const float4*)(feats + (long)g * 32);
    float4 f[8];
#pragma unroll
    for (int j = 0; j < 8; ++j) f[j] = fp[j];
    float a0 = 0, a1 = 0, a2 = 0, a3 = 0;
#pragma unroll
    for (int j = 0; j < 8; ++j) {
      a0 = fmaf(f[j].x, w[4 * j + 0], a0);
      a1 = fmaf(f[j].y, w[4 * j + 1], a1);
      a2 = fmaf(f[j].z, w[4 * j + 2], a2);
      a3 = fmaf(f[j].w, w[4 * j + 3], a3);
    }
    if (s < n_out) atomicAdd(out + ((long)s << 6) + lane, (a0 + a1) + (a2 + a3));
  }
}

__global__ __launch_bounds__(256) void stats_kernel(
    const float4* __restrict__ out, float* __restrict__ ws, long total4) {
  const long stride = (long)gridDim.x * blockDim.x;
  float s1[4] = {0.f, 0.f, 0.f, 0.f};
  float s2[4] = {0.f, 0.f, 0.f, 0.f};
  for (long i = (long)blockIdx.x * blockDim.x + threadIdx.x; i < total4; i += stride) {
    float4 x = out[i];
    s1[0] += x.x; s2[0] += x.x * x.x;
    s1[1] += x.y; s2[1] += x.y * x.y;
    s1[2] += x.z; s2[2] += x.z * x.z;
    s1[3] += x.w; s2[3] += x.w * x.w;
  }
  __shared__ float ls[128];
  if (threadIdx.x < 128) ls[threadIdx.x] = 0.f;
  __syncthreads();
  const int cb = (threadIdx.x << 2) & 63;
#pragma unroll
  for (int j = 0; j < 4; ++j) {
    atomicAdd(&ls[cb + j], s1[j]);
    atomicAdd(&ls[64 + cb + j], s2[j]);
  }
  __syncthreads();
  if (threadIdx.x < 128) atomicAdd(&ws[threadIdx.x], ls[threadIdx.x]);
}

extern "C" void kernel_launch(void* const* d_in, const int* in_sizes, int n_in,
                              void* d_out, int out_size, void* d_ws, size_t ws_size,
                              hipStream_t stream) {
  const float* feats = (const float*)d_in[0];
  const float* W     = (const float*)d_in[1];
  const float* gamma = (const float*)d_in[2];
  const float* beta  = (const float*)d_in[3];
  const int*   gidx  = (const int*)d_in[4];
  const int*   sidx  = (const int*)d_in[5];

  const int P = in_sizes[4] / 4;    // KVOL == 4
  const int n_out = out_size / 64;  // COUT == 64
  float* out = (float*)d_out;
  float* ws  = (float*)d_ws;
  const long total4 = (long)out_size / 4;

  char* wsb = (char*)d_ws;
  const size_t flags_off = 2048;
  const int nwords = (n_out + 16) / 16 + 1;  // covers s == n_out padding word
  const size_t flags_bytes = (size_t)nwords * 4;
  const size_t need = flags_off + flags_bytes;

  if (ws_size >= need) {
    unsigned* flags = (unsigned*)(wsb + flags_off);
    hipMemsetAsync(wsb, 0, 2048, stream);           // stats block
    hipMemsetAsync(flags, 0, flags_bytes, stream);  // flag table (486 KB)

    dim3 fgrid((P + 255) / 256, 4);
    flag_kernel<<<fgrid, 256, 0, stream>>>(sidx, flags, P, n_out);
    zero_multi_kernel<<<1024, 256, 0, stream>>>(flags, (float4*)out, nwords, n_out);

    const int rpw = 256;  // rules per wave (4 groups of 64 = 16 MFMA tiles)
    const int waves_per_k = (P + rpw - 1) / rpw;
    dim3 vgrid((waves_per_k + 3) / 4, 4);
    conv_mfma_kernel<<<vgrid, 256, 0, stream>>>(feats, W, gidx, sidx, flags,
                                                out, ws, P, n_out, rpw);
    finalize_stats_kernel<<<1, 64, 0, stream>>>(ws, gamma, beta, 1.0f / (float)n_out);
    normalize_kernel<<<2048, 256, 0, stream>>>((float4*)out, ws, total4);
  } else {
    hipMemsetAsync(d_out, 0, (size_t)out_size * sizeof(float), stream);
    hipMemsetAsync(d_ws, 0, 256 * sizeof(float), stream);
    dim3 sgrid(2048, 4);
    scatter_conv_kernel<<<sgrid, 256, 0, stream>>>(feats, W, gidx, sidx, out, P, n_out);
    stats_kernel<<<2048, 256, 0, stream>>>((const float4*)out, ws, total4);
    finalize_stats_kernel<<<1, 64, 0, stream>>>(ws, gamma, beta, 1.0f / (float)n_out);
    normalize_kernel<<<2048, 256, 0, stream>>>((float4*)out, ws, total4);
  }
}

// Round 16
// 525.288 us; speedup vs baseline: 1.0791x; 1.0177x over previous
//
#include <hip/hip_runtime.h>

#define EPS_LN 1e-4f

typedef short short8 __attribute__((ext_vector_type(8)));
typedef float f32x4 __attribute__((ext_vector_type(4)));

// f32 -> bf16 RTNE (bit trick; used only in one-time W setup)
__device__ __forceinline__ short f2bf(float f) {
  const unsigned u = __float_as_uint(f);
  return (short)((u + 0x7FFFu + ((u >> 16) & 1u)) >> 16);
}

// pack 2 f32 -> 2 bf16 in one VALU op (RTNE; low=a, high=b)
__device__ __forceinline__ unsigned cvt_pk_bf16(float a, float b) {
  unsigned r;
  asm("v_cvt_pk_bf16_f32 %0, %1, %2" : "=v"(r) : "v"(a), "v"(b));
  return r;
}

// ===========================================================================
// r12 evidence: conv at the random-access memory wall (~300us); normalize at
// f32 roofline (~165us). Ceiling arithmetic: 1.0GB of the 1.79GB ideal
// traffic is the f32 intermediate round-trip -> reducible to bf16.
// r13: single-contribution rows (~97%) store a PERMUTED bf16 row (128B) in
// ws (pos = (c&15)*4 + (c>>4) makes each lane's 4 channel values contiguous
// -> 2 cvt_pk + one 8B store); multi rows keep the f32 atomic path in out.
// Row-wise normalize reads bf16 (single) / f32 out (multi, rare) and writes
// coalesced f32. Saves ~470MB.
// ws: [0,1KB) stats | [2KB) flags | [align256) bf16 buf n_out*128B
// ===========================================================================

__global__ __launch_bounds__(256) void flag_kernel(
    const int* __restrict__ sidx, unsigned* __restrict__ flags, int P,
    int n_out) {
  const int k = blockIdx.y;
  const int p = blockIdx.x * blockDim.x + threadIdx.x;
  if (p >= P) return;
  const int s = sidx[k * P + p];
  if (s >= n_out) return;  // padding
  const unsigned sh = (s & 15) << 1;
  const unsigned old = atomicOr(&flags[s >> 4], 1u << sh);
  if (old & (1u << sh)) atomicOr(&flags[s >> 4], 2u << sh);  // multi (rare)
}

__global__ __launch_bounds__(256) void zero_multi_kernel(
    const unsigned* __restrict__ flags, float4* __restrict__ out, int nwords,
    int n_out) {
  const int stride = gridDim.x * blockDim.x;
  const float4 z = {0.f, 0.f, 0.f, 0.f};
  for (int w = blockIdx.x * blockDim.x + threadIdx.x; w < nwords; w += stride) {
    unsigned f = flags[w] & 0xAAAAAAAAu;  // multi bits
    while (f) {
      const int b = __builtin_ctz(f);
      f &= f - 1;
      const int r = (w << 4) + (b >> 1);
      if (r < n_out) {
        float4* row = out + ((size_t)r << 4);  // 64 floats
#pragma unroll
        for (int j = 0; j < 16; ++j) row[j] = z;
      }
    }
  }
}

__global__ __launch_bounds__(256) void conv_mfma_kernel(
    const float* __restrict__ feats, const float* __restrict__ W,
    const int* __restrict__ gidx, const int* __restrict__ sidx,
    const unsigned* __restrict__ flags, float* __restrict__ out,
    unsigned short* __restrict__ wsbuf, float* __restrict__ ws,
    int P, int n_out, int rpw) {
  const int lane = threadIdx.x & 63;
  const int l15 = lane & 15;
  const int lh = lane >> 4;  // 0..3
  const int k = blockIdx.y;
  const int wv = blockIdx.x * (blockDim.x >> 6) + (threadIdx.x >> 6);

  __shared__ float ls[128];
  if (threadIdx.x < 128) ls[threadIdx.x] = 0.f;
  __syncthreads();

  // B fragments: wb[m][j] = W[k][ 8*lh+j ][ 16m + l15 ] as bf16
  short8 wb[4];
#pragma unroll
  for (int m = 0; m < 4; ++m) {
#pragma unroll
    for (int j = 0; j < 8; ++j) {
      const int kk = (lh << 3) + j;
      wb[m][j] = f2bf(W[(((k << 5) + kk) << 6) + (m << 4) + l15]);
    }
  }

  const long base = (long)k * P;
  const int start = wv * rpw;
  const int end = min(start + rpw, P);
  float s1[4] = {0.f, 0.f, 0.f, 0.f}, s2[4] = {0.f, 0.f, 0.f, 0.f};
  const f32x4 zero = {0.f, 0.f, 0.f, 0.f};

  if (start < end) {
    // group (64 rules) index state; sp = (s<<1) | multi
    int g = 0, sp = (n_out << 1);
    {
      const int pg = start + lane;
      if (pg < end) {
        g = gidx[base + pg];
        const int s = sidx[base + pg];
        const unsigned mu = (flags[s >> 4] >> (((s & 15) << 1) + 1)) & 1u;
        sp = (s << 1) | (int)mu;
      }
    }

    for (int gs = start; gs < end; gs += 64) {
      // ---- issue all 4 tiles' gathers: 64 random 128B rows in flight ----
      float4 F[8];
#pragma unroll
      for (int t = 0; t < 4; ++t) {
        const int gq = __shfl(g, (t << 4) + l15);  // rule for my A-row
        const float4* fp = (const float4*)feats + ((size_t)gq << 3) + (lh << 1);
        F[2 * t] = fp[0];
        F[2 * t + 1] = fp[1];
      }
      // ---- prefetch next group's indices under this group's compute ----
      int gN = 0, spN = (n_out << 1);
      {
        const int pg = gs + 64 + lane;
        if (pg < end) {
          gN = gidx[base + pg];
          const int s = sidx[base + pg];
          const unsigned mu = (flags[s >> 4] >> (((s & 15) << 1) + 1)) & 1u;
          spN = (s << 1) | (int)mu;
        }
      }
      // ---- per tile: cvt_pk -> 4 MFMA -> classified store + stats ----
#pragma unroll
      for (int t = 0; t < 4; ++t) {
        unsigned au0 = cvt_pk_bf16(F[2 * t].x, F[2 * t].y);
        unsigned au1 = cvt_pk_bf16(F[2 * t].z, F[2 * t].w);
        unsigned au2 = cvt_pk_bf16(F[2 * t + 1].x, F[2 * t + 1].y);
        unsigned au3 = cvt_pk_bf16(F[2 * t + 1].z, F[2 * t + 1].w);
        short8 a;
        ((unsigned*)&a)[0] = au0; ((unsigned*)&a)[1] = au1;
        ((unsigned*)&a)[2] = au2; ((unsigned*)&a)[3] = au3;
        const f32x4 d0 = __builtin_amdgcn_mfma_f32_16x16x32_bf16(a, wb[0], zero, 0, 0, 0);
        const f32x4 d1 = __builtin_amdgcn_mfma_f32_16x16x32_bf16(a, wb[1], zero, 0, 0, 0);
        const f32x4 d2 = __builtin_amdgcn_mfma_f32_16x16x32_bf16(a, wb[2], zero, 0, 0, 0);
        const f32x4 d3 = __builtin_amdgcn_mfma_f32_16x16x32_bf16(a, wb[3], zero, 0, 0, 0);
#pragma unroll
        for (int q = 0; q < 4; ++q) {
          const int spq = __shfl(sp, (t << 4) + (lh << 2) + q);  // rule 4lh+q
          const int srow = spq >> 1;
          if (srow < n_out) {
            const float v0 = d0[q], v1 = d1[q], v2 = d2[q], v3 = d3[q];
            s1[0] += v0; s1[1] += v1; s1[2] += v2; s1[3] += v3;
            if (spq & 1) {  // multi (~3%): f32 atomic + telescoped sumsq
              const size_t rb = ((size_t)srow << 6) + l15;
              const float o0 = atomicAdd(out + rb, v0);
              const float o1 = atomicAdd(out + rb + 16, v1);
              const float o2 = atomicAdd(out + rb + 32, v2);
              const float o3 = atomicAdd(out + rb + 48, v3);
              s2[0] = fmaf(v0, 2.f * o0 + v0, s2[0]);
              s2[1] = fmaf(v1, 2.f * o1 + v1, s2[1]);
              s2[2] = fmaf(v2, 2.f * o2 + v2, s2[2]);
              s2[3] = fmaf(v3, 2.f * o3 + v3, s2[3]);
            } else {  // single: permuted bf16 row, one 8B store
              s2[0] = fmaf(v0, v0, s2[0]);
              s2[1] = fmaf(v1, v1, s2[1]);
              s2[2] = fmaf(v2, v2, s2[2]);
              s2[3] = fmaf(v3, v3, s2[3]);
              uint2 pk;
              pk.x = cvt_pk_bf16(v0, v1);
              pk.y = cvt_pk_bf16(v2, v3);
              *(uint2*)(wsbuf + ((size_t)srow << 6) + (l15 << 2)) = pk;
            }
          }
        }
      }
      g = gN;
      sp = spN;
    }
  }

#pragma unroll
  for (int m = 0; m < 4; ++m) {
    atomicAdd(&ls[(m << 4) + l15], s1[m]);
    atomicAdd(&ls[64 + (m << 4) + l15], s2[m]);
  }
  __syncthreads();
  if (threadIdx.x < 128) atomicAdd(&ws[threadIdx.x], ls[threadIdx.x]);
}

__global__ void finalize_stats_kernel(float* __restrict__ ws,
                                      const float* __restrict__ gamma,
                                      const float* __restrict__ beta,
                                      float inv_n) {
  const int c = threadIdx.x;  // 64 threads
  const float mean = ws[c] * inv_n;
  const float var = ws[64 + c] * inv_n - mean * mean;
  const float sc = rsqrtf(var + EPS_LN) * gamma[c];
  ws[128 + c] = sc;
  ws[192 + c] = beta[c] - mean * sc;
}

// Row-wise normalize: single rows from permuted bf16 ws buf, multi rows
// (wave-uniform rare branch) from f32 out; coalesced 256B f32 write.
__global__ __launch_bounds__(256) void normalize_rows_kernel(
    const unsigned short* __restrict__ wsbuf, const unsigned* __restrict__ flags,
    const float* __restrict__ ws, float* __restrict__ out, int n_out) {
  const int lane = threadIdx.x & 63;
  const float sc = ws[128 + lane];
  const float sh = ws[192 + lane];
  const int poff = ((lane & 15) << 2) + (lane >> 4);  // un-permute position
  const int wave = (blockIdx.x * blockDim.x + threadIdx.x) >> 6;
  const int wstep = (gridDim.x * blockDim.x) >> 6;

  for (int r = wave * 2; r < n_out; r += wstep * 2) {
    const int r1 = r + 1;
    const bool has1 = r1 < n_out;
    const bool mu0 = (flags[r >> 4] >> (((r & 15) << 1) + 1)) & 1u;
    const bool mu1 = has1 ? ((flags[r1 >> 4] >> (((r1 & 15) << 1) + 1)) & 1u) : false;
    float v0, v1 = 0.f;
    if (mu0) v0 = out[((size_t)r << 6) + lane];
    else v0 = __uint_as_float((unsigned)wsbuf[((size_t)r << 6) + poff] << 16);
    if (has1) {
      if (mu1) v1 = out[((size_t)r1 << 6) + lane];
      else v1 = __uint_as_float((unsigned)wsbuf[((size_t)r1 << 6) + poff] << 16);
    }
    out[((size_t)r << 6) + lane] = fmaxf(fmaf(v0, sc, sh), 0.f);
    if (has1) out[((size_t)r1 << 6) + lane] = fmaxf(fmaf(v1, sc, sh), 0.f);
  }
}

// ---------------- fallback (if ws too small): r2 path ----------------
__global__ __launch_bounds__(256) void scatter_conv_kernel(
    const float* __restrict__ feats, const float* __restrict__ W,
    const int* __restrict__ gidx, const int* __restrict__ sidx,
    float* __restrict__ out, int P, int n_out) {
  const int lane = threadIdx.x & 63;
  const int k = blockIdx.y;
  const int wave = blockIdx.x * (blockDim.x >> 6) + (threadIdx.x >> 6);
  const int stride = gridDim.x * (blockDim.x >> 6);
  float w[32];
#pragma unroll
  for (int c = 0; c < 32; ++c) w[c] = W[((k * 32 + c) << 6) + lane];
  const int base = k * P;
  for (int p = wave; p < P; p += stride) {
    const int g = gidx[base + p];
    const int s = sidx[base + p];
    const float4* fp = (const float4*)(feats + (long)g * 32);
    float4 f[8];
#pragma unroll
    for (int j = 0; j < 8; ++j) f[j] = fp[j];
    float a0 = 0, a1 = 0, a2 = 0, a3 = 0;
#pragma unroll
    for (int j = 0; j < 8; ++j) {
      a0 = fmaf(f[j].x, w[4 * j + 0], a0);
      a1 = fmaf(f[j].y, w[4 * j + 1], a1);
      a2 = fmaf(f[j].z, w[4 * j + 2], a2);
      a3 = fmaf(f[j].w, w[4 * j + 3], a3);
    }
    if (s < n_out) atomicAdd(out + ((long)s << 6) + lane, (a0 + a1) + (a2 + a3));
  }
}

__global__ __launch_bounds__(256) void stats_kernel(
    const float4* __restrict__ out, float* __restrict__ ws, long total4) {
  const long stride = (long)gridDim.x * blockDim.x;
  float s1[4] = {0.f, 0.f, 0.f, 0.f};
  float s2[4] = {0.f, 0.f, 0.f, 0.f};
  for (long i = (long)blockIdx.x * blockDim.x + threadIdx.x; i < total4; i += stride) {
    float4 x = out[i];
    s1[0] += x.x; s2[0] += x.x * x.x;
    s1[1] += x.y; s2[1] += x.y * x.y;
    s1[2] += x.z; s2[2] += x.z * x.z;
    s1[3] += x.w; s2[3] += x.w * x.w;
  }
  __shared__ float ls[128];
  if (threadIdx.x < 128) ls[threadIdx.x] = 0.f;
  __syncthreads();
  const int cb = (threadIdx.x << 2) & 63;
#pragma unroll
  for (int j = 0; j < 4; ++j) {
    atomicAdd(&ls[cb + j], s1[j]);
    atomicAdd(&ls[64 + cb + j], s2[j]);
  }
  __syncthreads();
  if (threadIdx.x < 128) atomicAdd(&ws[threadIdx.x], ls[threadIdx.x]);
}

__global__ __launch_bounds__(256) void normalize_kernel(
    float4* __restrict__ out, const float* __restrict__ ws, long total4) {
  const long stride = (long)gridDim.x * blockDim.x;
  const int cb = (threadIdx.x << 2) & 63;
  const float4 sc = *(const float4*)(ws + 128 + cb);
  const float4 sh = *(const float4*)(ws + 192 + cb);
  for (long i = (long)blockIdx.x * blockDim.x + threadIdx.x; i < total4; i += stride) {
    float4 x = out[i];
    x.x = fmaxf(fmaf(x.x, sc.x, sh.x), 0.f);
    x.y = fmaxf(fmaf(x.y, sc.y, sh.y), 0.f);
    x.z = fmaxf(fmaf(x.z, sc.z, sh.z), 0.f);
    x.w = fmaxf(fmaf(x.w, sc.w, sh.w), 0.f);
    out[i] = x;
  }
}

extern "C" void kernel_launch(void* const* d_in, const int* in_sizes, int n_in,
                              void* d_out, int out_size, void* d_ws, size_t ws_size,
                              hipStream_t stream) {
  const float* feats = (const float*)d_in[0];
  const float* W     = (const float*)d_in[1];
  const float* gamma = (const float*)d_in[2];
  const float* beta  = (const float*)d_in[3];
  const int*   gidx  = (const int*)d_in[4];
  const int*   sidx  = (const int*)d_in[5];

  const int P = in_sizes[4] / 4;    // KVOL == 4
  const int n_out = out_size / 64;  // COUT == 64
  float* out = (float*)d_out;
  float* ws  = (float*)d_ws;
  const long total4 = (long)out_size / 4;

  char* wsb = (char*)d_ws;
  const size_t flags_off = 2048;
  const int nwords = (n_out + 16) / 16 + 1;  // covers s == n_out padding word
  const size_t flags_bytes = (size_t)nwords * 4;
  const size_t buf_off = (flags_off + flags_bytes + 255) & ~(size_t)255;
  const size_t need = buf_off + (size_t)n_out * 128;

  if (ws_size >= need) {
    unsigned* flags = (unsigned*)(wsb + flags_off);
    unsigned short* wsbuf = (unsigned short*)(wsb + buf_off);
    hipMemsetAsync(wsb, 0, 2048, stream);           // stats block
    hipMemsetAsync(flags, 0, flags_bytes, stream);  // flag table (486 KB)

    dim3 fgrid((P + 255) / 256, 4);
    flag_kernel<<<fgrid, 256, 0, stream>>>(sidx, flags, P, n_out);
    zero_multi_kernel<<<1024, 256, 0, stream>>>(flags, (float4*)out, nwords, n_out);

    const int rpw = 256;  // rules per wave (4 groups of 64 = 16 MFMA tiles)
    const int waves_per_k = (P + rpw - 1) / rpw;
    dim3 vgrid((waves_per_k + 3) / 4, 4);
    conv_mfma_kernel<<<vgrid, 256, 0, stream>>>(feats, W, gidx, sidx, flags,
                                                out, wsbuf, ws, P, n_out, rpw);
    finalize_stats_kernel<<<1, 64, 0, stream>>>(ws, gamma, beta, 1.0f / (float)n_out);
    normalize_rows_kernel<<<2048, 256, 0, stream>>>(wsbuf, flags, ws, out, n_out);
  } else {
    hipMemsetAsync(d_out, 0, (size_t)out_size * sizeof(float), stream);
    hipMemsetAsync(d_ws, 0, 256 * sizeof(float), stream);
    dim3 sgrid(2048, 4);
    scatter_conv_kernel<<<sgrid, 256, 0, stream>>>(feats, W, gidx, sidx, out, P, n_out);
    stats_kernel<<<2048, 256, 0, stream>>>((const float4*)out, ws, total4);
    finalize_stats_kernel<<<1, 64, 0, stream>>>(ws, gamma, beta, 1.0f / (float)n_out);
    normalize_kernel<<<2048, 256, 0, stream>>>((float4*)out, ws, total4);
  }
}